// Round 4
// baseline (552.384 us; speedup 1.0000x reference)
//
#include <hip/hip_runtime.h>
#include <stdint.h>

#define NLEV 16
#define LOG2_T 19
#define TMASK ((1u << LOG2_T) - 1u)
#define P1 2654435761u
#define P2 805459861u

typedef float floatx4 __attribute__((ext_vector_type(4)));
typedef float floatx2 __attribute__((ext_vector_type(2)));

#define PTS1 4
#define BLOCK1 256
#define CHUNK1 (BLOCK1 * PTS1)   // 1024 points per block

// ---- one point, one level (exact fp32, same FMA order as reference) ----
// R3 (kept): levels are L2 scattered-REQUEST-throughput bound (~10 req/cy/XCD;
// R2's 4x MLP increase gave zero gain -> not latency-bound). PRIMES[0]==1 means
// the aligned 16B pair at idx&~1 always holds corners {x&~1, (x&~1)+1}; for
// even x one dwordx4 covers both x-corners. avg requests/point: 8 -> 6 (minimal
// for this layout: odd-x corner x+1 sits in a different pair, x-dependent).
__device__ __forceinline__ floatx2 encode_point_level(
    float xn, float yn, float zn, float res,
    const float* __restrict__ tbl_f)      // 2 floats per entry
{
    const float posx = xn * res;
    const float posy = yn * res;
    const float posz = zn * res;
    const float flx = floorf(posx);
    const float fly = floorf(posy);
    const float flz = floorf(posz);
    const float fx = posx - flx, fy = posy - fly, fz = posz - flz;
    const int ix = (int)flx, iy = (int)fly, iz = (int)flz;

    const uint32_t ux  = (uint32_t)ix;
    const uint32_t hy0 = (uint32_t)iy * P1;
    const uint32_t hy1 = (uint32_t)(iy + 1) * P1;
    const uint32_t hz0 = (uint32_t)iz * P2;
    const uint32_t hz1 = (uint32_t)(iz + 1) * P2;

    // j: bit1 = y-corner, bit0 = z-corner  (matches ref order c = x*4 + j)
    const uint32_t byz[4] = { hy0 ^ hz0, hy0 ^ hz1, hy1 ^ hz0, hy1 ^ hz1 };

    uint32_t ia[4];
    floatx4  pr[4];
    #pragma unroll
    for (int j = 0; j < 4; ++j) {
        ia[j] = (byz[j] ^ ux) & TMASK;
        // aligned 16B pair containing entry ia[j] (and, if x even, also ia[j]^1)
        pr[j] = *(const floatx4*)(tbl_f + (size_t)(ia[j] & ~1u) * 2);
    }

    floatx2 f0[4], f1[4];
    #pragma unroll
    for (int j = 0; j < 4; ++j) {
        const floatx2 lo = { pr[j].x, pr[j].y };
        const floatx2 hi = { pr[j].z, pr[j].w };
        const bool odd_entry = (ia[j] & 1u) != 0u;
        f0[j] = odd_entry ? hi : lo;      // entry ia[j]       (corner x)
        f1[j] = odd_entry ? lo : hi;      // entry ia[j]^1     (= corner x+1 iff x even)
    }

    if (ux & 1u) {                         // x odd: corner x+1 needs its own gather
        const uint32_t ux1 = ux + 1u;
        #pragma unroll
        for (int j = 0; j < 4; ++j) {
            const uint32_t ib = (byz[j] ^ ux1) & TMASK;
            f1[j] = *(const floatx2*)(tbl_f + (size_t)ib * 2);
        }
    }

    const float gx = 1.f - fx, gy = 1.f - fy, gz = 1.f - fz;
    const float wyv[2] = {gy, fy};
    const float wzv[2] = {gz, fz};

    // identical FMA order to the verified kernel: c = 0..7, c = x*4 + y*2 + z
    float s0 = 0.f, s1 = 0.f;
    #pragma unroll
    for (int j = 0; j < 4; ++j) {
        const float w = (gx * wyv[(j >> 1) & 1]) * wzv[j & 1];
        s0 = fmaf(w, f0[j].x, s0);
        s1 = fmaf(w, f0[j].y, s1);
    }
    #pragma unroll
    for (int j = 0; j < 4; ++j) {
        const float w = (fx * wyv[(j >> 1) & 1]) * wzv[j & 1];
        s0 = fmaf(w, f1[j].x, s0);
        s1 = fmaf(w, f1[j].y, s1);
    }
    floatx2 r = {s0, s1};
    return r;
}

// ---- phase 1: one level per XCD (level = base + blockIdx%8), ws[l][N][2] ----
// R4 probe: x streams 12MB per XCD through the 4MB L2 that also holds the
// level's table (footprint == L2 size) -> ~3x full table churn per launch
// from x insertions alone (196K lines vs 65K table lines). Mark x loads
// non-temporal (evict-first) so the table stays resident. Tests the
// miss-throttle hypothesis at zero correctness risk. ws stores already NT.
__global__ __launch_bounds__(BLOCK1) void level_kernel(
    const float* __restrict__ x,
    const float* __restrict__ bb,
    const float* __restrict__ table_f,
    float* __restrict__ ws,
    int n, int level_base)
{
    const int level = level_base + (int)(blockIdx.x & 7);
    const int chunk = (int)(blockIdx.x >> 3);
    const int base  = chunk * CHUNK1 + (int)threadIdx.x;

    const float bx0 = bb[0], by0 = bb[1], bz0 = bb[2];
    const float bx1 = bb[3], by1 = bb[4], bz1 = bb[5];

    const float res = (float)(16 << level);      // floor(16*2^l) exact
    const float* __restrict__ tbl =
        table_f + (((size_t)level << LOG2_T) * 2);
    floatx2* __restrict__ wrow = (floatx2*)ws + (size_t)level * n;

    #pragma unroll
    for (int k = 0; k < PTS1; ++k) {
        const int p = base + k * BLOCK1;
        if (p >= n) continue;
        const float px = __builtin_nontemporal_load(x + 3 * p + 0);
        const float py = __builtin_nontemporal_load(x + 3 * p + 1);
        const float pz = __builtin_nontemporal_load(x + 3 * p + 2);
        const float xn = (px - bx0) / (bx1 - bx0);
        const float yn = (py - by0) / (by1 - by0);
        const float zn = (pz - bz0) / (bz1 - bz0);
        floatx2 r = encode_point_level(xn, yn, zn, res, tbl);
        // non-temporal: don't evict the resident table from L2
        __builtin_nontemporal_store(r, wrow + p);
    }
}

// ---- phase 2: transpose ws[16][N][2] -> enc[N][32] via LDS, compute mask ----
// (R1 win: LDS-staged contiguous stores removed 3x HBM write amplification;
//  transpose now ~25us. Do not revert to per-lane strided NT stores.)
__global__ __launch_bounds__(256) void transpose_kernel(
    const float* __restrict__ ws,
    const float* __restrict__ x,
    const float* __restrict__ bb,
    float* __restrict__ enc_out,
    float* __restrict__ mask_out,
    int n)
{
    __shared__ float tile[256 * 33];

    const int tid = (int)threadIdx.x;
    const int b0  = (int)blockIdx.x * 256;
    const int p   = b0 + tid;

    const floatx2* __restrict__ w = (const floatx2*)ws;

    if (p < n) {
        float* row = tile + tid * 33;
        #pragma unroll
        for (int l = 0; l < NLEV; ++l) {
            floatx2 v = w[(size_t)l * n + p];     // lane-contiguous: coalesced
            row[2 * l + 0] = v.x;
            row[2 * l + 1] = v.y;
        }

        const float bx0 = bb[0], by0 = bb[1], bz0 = bb[2];
        const float bx1 = bb[3], by1 = bb[4], bz1 = bb[5];
        const float xn = (x[3 * p + 0] - bx0) / (bx1 - bx0);
        const float yn = (x[3 * p + 1] - by0) / (by1 - by0);
        const float zn = (x[3 * p + 2] - bz0) / (bz1 - bz0);
        const bool inb = (xn > 0.f) & (xn < 1.f) &
                         (yn > 0.f) & (yn < 1.f) &
                         (zn > 0.f) & (zn < 1.f);
        __builtin_nontemporal_store(inb ? 1.0f : 0.0f, mask_out + p);
    }
    __syncthreads();

    const int npts = (n - b0 < 256) ? (n - b0) : 256;
    floatx4* const eb = (floatx4*)(enc_out + (size_t)b0 * (2 * NLEV));

    if (npts == 256) {
        #pragma unroll
        for (int it = 0; it < 8; ++it) {
            const int c  = it * 256 + tid;        // float4 chunk within block tile
            const int pp = c >> 3;                // point within block
            const int jj = (c & 7) << 2;          // feature word
            const float* s = tile + pp * 33 + jj;
            floatx4 v = { s[0], s[1], s[2], s[3] };
            __builtin_nontemporal_store(v, eb + c);   // lanes contiguous: 1KiB/wave
        }
    } else {
        for (int it = 0; it < 8; ++it) {
            const int c  = it * 256 + tid;
            const int pp = c >> 3;
            if (pp < npts) {
                const int jj = (c & 7) << 2;
                const float* s = tile + pp * 33 + jj;
                floatx4 v = { s[0], s[1], s[2], s[3] };
                __builtin_nontemporal_store(v, eb + c);
            }
        }
    }
}

// ---- fallback: direct single-kernel version (verified correct) ----
__global__ __launch_bounds__(256) void hashenc_direct(
    const float* __restrict__ x,
    const float* __restrict__ bb,
    const float* __restrict__ table_f,
    float* __restrict__ enc_out,
    float* __restrict__ mask_out,
    int n)
{
    const int i = blockIdx.x * 256 + (int)threadIdx.x;
    if (i >= n) return;

    const float bx0 = bb[0], by0 = bb[1], bz0 = bb[2];
    const float bx1 = bb[3], by1 = bb[4], bz1 = bb[5];
    const float xn = (x[3 * i + 0] - bx0) / (bx1 - bx0);
    const float yn = (x[3 * i + 1] - by0) / (by1 - by0);
    const float zn = (x[3 * i + 2] - bz0) / (bz1 - bz0);
    const bool inb = (xn > 0.f) & (xn < 1.f) &
                     (yn > 0.f) & (yn < 1.f) &
                     (zn > 0.f) & (zn < 1.f);

    float enc[2 * NLEV];
    for (int l = 0; l < NLEV; ++l) {
        const float res = (float)(16 << l);
        floatx2 r = encode_point_level(xn, yn, zn, res,
                                       table_f + (((size_t)l << LOG2_T) * 2));
        enc[2 * l + 0] = r.x;
        enc[2 * l + 1] = r.y;
    }
    floatx4* o = (floatx4*)(enc_out + (size_t)i * (2 * NLEV));
    #pragma unroll
    for (int k = 0; k < (2 * NLEV) / 4; ++k) {
        floatx4 v = { enc[4 * k + 0], enc[4 * k + 1],
                      enc[4 * k + 2], enc[4 * k + 3] };
        __builtin_nontemporal_store(v, o + k);
    }
    __builtin_nontemporal_store(inb ? 1.0f : 0.0f, mask_out + i);
}

extern "C" void kernel_launch(void* const* d_in, const int* in_sizes, int n_in,
                              void* d_out, int out_size, void* d_ws, size_t ws_size,
                              hipStream_t stream) {
    const float* x     = (const float*)d_in[0];
    const float* bb    = (const float*)d_in[1];
    const float* table = (const float*)d_in[2];
    const int n = in_sizes[0] / 3;

    float* enc_out  = (float*)d_out;
    float* mask_out = enc_out + (size_t)n * (2 * NLEV);

    const size_t ws_need = (size_t)NLEV * (size_t)n * 2 * sizeof(float);
    if (ws_size >= ws_need) {
        float* ws = (float*)d_ws;
        const int chunks = (n + CHUNK1 - 1) / CHUNK1;
        const int grid1 = chunks * 8;
        level_kernel<<<grid1, BLOCK1, 0, stream>>>(x, bb, table, ws, n, 0);
        level_kernel<<<grid1, BLOCK1, 0, stream>>>(x, bb, table, ws, n, 8);
        const int grid2 = (n + 255) / 256;
        transpose_kernel<<<grid2, 256, 0, stream>>>(ws, x, bb, enc_out, mask_out, n);
    } else {
        const int grid = (n + 255) / 256;
        hashenc_direct<<<grid, 256, 0, stream>>>(x, bb, table, enc_out, mask_out, n);
    }
}

// Round 5
// 512.848 us; speedup vs baseline: 1.0771x; 1.0771x over previous
//
#include <hip/hip_runtime.h>
#include <stdint.h>

#define NLEV 16
#define LOG2_T 19
#define TMASK ((1u << LOG2_T) - 1u)
#define P1 2654435761u
#define P2 805459861u

typedef float floatx4 __attribute__((ext_vector_type(4)));
typedef float floatx2 __attribute__((ext_vector_type(2)));

#define PTS1 4
#define BLOCK1 256
#define CHUNK1 (BLOCK1 * PTS1)   // 1024 points per block

// ---- one point, one level (exact fp32, same FMA order as reference) ----
// R3 (kept): levels are L2 scattered-REQUEST-throughput bound (~10.8 req/cy/XCD
// = ~67% of 16 channels, the random-banking ceiling). R2: 4x MLP -> null (not
// latency-bound). R4: NT x-loads cut FETCH 195->129MB but SLOWED levels 8%
// (not miss-bound; L1-bypass added L2 requests) -- REVERTED, do not re-add.
// PRIMES[0]==1 pair trick: aligned 16B pair at idx&~1 holds corners
// {x&~1,(x&~1)+1}; even x needs one dwordx4 for both x-corners.
// avg requests/point: 8 -> 6 (minimal for this layout).
__device__ __forceinline__ floatx2 encode_point_level(
    float xn, float yn, float zn, float res,
    const float* __restrict__ tbl_f)      // 2 floats per entry
{
    const float posx = xn * res;
    const float posy = yn * res;
    const float posz = zn * res;
    const float flx = floorf(posx);
    const float fly = floorf(posy);
    const float flz = floorf(posz);
    const float fx = posx - flx, fy = posy - fly, fz = posz - flz;
    const int ix = (int)flx, iy = (int)fly, iz = (int)flz;

    const uint32_t ux  = (uint32_t)ix;
    const uint32_t hy0 = (uint32_t)iy * P1;
    const uint32_t hy1 = (uint32_t)(iy + 1) * P1;
    const uint32_t hz0 = (uint32_t)iz * P2;
    const uint32_t hz1 = (uint32_t)(iz + 1) * P2;

    // j: bit1 = y-corner, bit0 = z-corner  (matches ref order c = x*4 + j)
    const uint32_t byz[4] = { hy0 ^ hz0, hy0 ^ hz1, hy1 ^ hz0, hy1 ^ hz1 };

    uint32_t ia[4];
    floatx4  pr[4];
    #pragma unroll
    for (int j = 0; j < 4; ++j) {
        ia[j] = (byz[j] ^ ux) & TMASK;
        // aligned 16B pair containing entry ia[j] (and, if x even, also ia[j]^1)
        pr[j] = *(const floatx4*)(tbl_f + (size_t)(ia[j] & ~1u) * 2);
    }

    floatx2 f0[4], f1[4];
    #pragma unroll
    for (int j = 0; j < 4; ++j) {
        const floatx2 lo = { pr[j].x, pr[j].y };
        const floatx2 hi = { pr[j].z, pr[j].w };
        const bool odd_entry = (ia[j] & 1u) != 0u;
        f0[j] = odd_entry ? hi : lo;      // entry ia[j]       (corner x)
        f1[j] = odd_entry ? lo : hi;      // entry ia[j]^1     (= corner x+1 iff x even)
    }

    if (ux & 1u) {                         // x odd: corner x+1 needs its own gather
        const uint32_t ux1 = ux + 1u;
        #pragma unroll
        for (int j = 0; j < 4; ++j) {
            const uint32_t ib = (byz[j] ^ ux1) & TMASK;
            f1[j] = *(const floatx2*)(tbl_f + (size_t)ib * 2);
        }
    }

    const float gx = 1.f - fx, gy = 1.f - fy, gz = 1.f - fz;
    const float wyv[2] = {gy, fy};
    const float wzv[2] = {gz, fz};

    // identical FMA order to the verified kernel: c = 0..7, c = x*4 + y*2 + z
    float s0 = 0.f, s1 = 0.f;
    #pragma unroll
    for (int j = 0; j < 4; ++j) {
        const float w = (gx * wyv[(j >> 1) & 1]) * wzv[j & 1];
        s0 = fmaf(w, f0[j].x, s0);
        s1 = fmaf(w, f0[j].y, s1);
    }
    #pragma unroll
    for (int j = 0; j < 4; ++j) {
        const float w = (fx * wyv[(j >> 1) & 1]) * wzv[j & 1];
        s0 = fmaf(w, f1[j].x, s0);
        s1 = fmaf(w, f1[j].y, s1);
    }
    floatx2 r = {s0, s1};
    return r;
}

// ---- phase 1: one level per XCD (level = base + blockIdx%8), ws[l][N][2] ----
// R2 lesson: batching 32 gathers in flight was null (-6%) -> request-throughput
// bound, not latency bound. Keep the simple per-point loop.
// R4 lesson: NT hints on x loads regress 8% (L1 bypass -> extra L2 requests).
// Plain cached x loads; NT store on ws is fine (coalesced, tested throughout).
__global__ __launch_bounds__(BLOCK1) void level_kernel(
    const float* __restrict__ x,
    const float* __restrict__ bb,
    const float* __restrict__ table_f,
    float* __restrict__ ws,
    int n, int level_base)
{
    const int level = level_base + (int)(blockIdx.x & 7);
    const int chunk = (int)(blockIdx.x >> 3);
    const int base  = chunk * CHUNK1 + (int)threadIdx.x;

    const float bx0 = bb[0], by0 = bb[1], bz0 = bb[2];
    const float bx1 = bb[3], by1 = bb[4], bz1 = bb[5];

    const float res = (float)(16 << level);      // floor(16*2^l) exact
    const float* __restrict__ tbl =
        table_f + (((size_t)level << LOG2_T) * 2);
    floatx2* __restrict__ wrow = (floatx2*)ws + (size_t)level * n;

    #pragma unroll
    for (int k = 0; k < PTS1; ++k) {
        const int p = base + k * BLOCK1;
        if (p >= n) continue;
        const float xn = (x[3 * p + 0] - bx0) / (bx1 - bx0);
        const float yn = (x[3 * p + 1] - by0) / (by1 - by0);
        const float zn = (x[3 * p + 2] - bz0) / (bz1 - bz0);
        floatx2 r = encode_point_level(xn, yn, zn, res, tbl);
        // non-temporal: don't evict the resident table from L2
        __builtin_nontemporal_store(r, wrow + p);
    }
}

// ---- phase 2: transpose ws[16][N][2] -> enc[N][32] via LDS, compute mask ----
// (R1 win: LDS-staged contiguous stores removed 3x HBM write amplification;
//  transpose now ~25us. Do not revert to per-lane strided NT stores.)
__global__ __launch_bounds__(256) void transpose_kernel(
    const float* __restrict__ ws,
    const float* __restrict__ x,
    const float* __restrict__ bb,
    float* __restrict__ enc_out,
    float* __restrict__ mask_out,
    int n)
{
    __shared__ float tile[256 * 33];

    const int tid = (int)threadIdx.x;
    const int b0  = (int)blockIdx.x * 256;
    const int p   = b0 + tid;

    const floatx2* __restrict__ w = (const floatx2*)ws;

    if (p < n) {
        float* row = tile + tid * 33;
        #pragma unroll
        for (int l = 0; l < NLEV; ++l) {
            floatx2 v = w[(size_t)l * n + p];     // lane-contiguous: coalesced
            row[2 * l + 0] = v.x;
            row[2 * l + 1] = v.y;
        }

        const float bx0 = bb[0], by0 = bb[1], bz0 = bb[2];
        const float bx1 = bb[3], by1 = bb[4], bz1 = bb[5];
        const float xn = (x[3 * p + 0] - bx0) / (bx1 - bx0);
        const float yn = (x[3 * p + 1] - by0) / (by1 - by0);
        const float zn = (x[3 * p + 2] - bz0) / (bz1 - bz0);
        const bool inb = (xn > 0.f) & (xn < 1.f) &
                         (yn > 0.f) & (yn < 1.f) &
                         (zn > 0.f) & (zn < 1.f);
        __builtin_nontemporal_store(inb ? 1.0f : 0.0f, mask_out + p);
    }
    __syncthreads();

    const int npts = (n - b0 < 256) ? (n - b0) : 256;
    floatx4* const eb = (floatx4*)(enc_out + (size_t)b0 * (2 * NLEV));

    if (npts == 256) {
        #pragma unroll
        for (int it = 0; it < 8; ++it) {
            const int c  = it * 256 + tid;        // float4 chunk within block tile
            const int pp = c >> 3;                // point within block
            const int jj = (c & 7) << 2;          // feature word
            const float* s = tile + pp * 33 + jj;
            floatx4 v = { s[0], s[1], s[2], s[3] };
            __builtin_nontemporal_store(v, eb + c);   // lanes contiguous: 1KiB/wave
        }
    } else {
        for (int it = 0; it < 8; ++it) {
            const int c  = it * 256 + tid;
            const int pp = c >> 3;
            if (pp < npts) {
                const int jj = (c & 7) << 2;
                const float* s = tile + pp * 33 + jj;
                floatx4 v = { s[0], s[1], s[2], s[3] };
                __builtin_nontemporal_store(v, eb + c);
            }
        }
    }
}

// ---- fallback: direct single-kernel version (verified correct) ----
__global__ __launch_bounds__(256) void hashenc_direct(
    const float* __restrict__ x,
    const float* __restrict__ bb,
    const float* __restrict__ table_f,
    float* __restrict__ enc_out,
    float* __restrict__ mask_out,
    int n)
{
    const int i = blockIdx.x * 256 + (int)threadIdx.x;
    if (i >= n) return;

    const float bx0 = bb[0], by0 = bb[1], bz0 = bb[2];
    const float bx1 = bb[3], by1 = bb[4], bz1 = bb[5];
    const float xn = (x[3 * i + 0] - bx0) / (bx1 - bx0);
    const float yn = (x[3 * i + 1] - by0) / (by1 - by0);
    const float zn = (x[3 * i + 2] - bz0) / (bz1 - bz0);
    const bool inb = (xn > 0.f) & (xn < 1.f) &
                     (yn > 0.f) & (yn < 1.f) &
                     (zn > 0.f) & (zn < 1.f);

    float enc[2 * NLEV];
    for (int l = 0; l < NLEV; ++l) {
        const float res = (float)(16 << l);
        floatx2 r = encode_point_level(xn, yn, zn, res,
                                       table_f + (((size_t)l << LOG2_T) * 2));
        enc[2 * l + 0] = r.x;
        enc[2 * l + 1] = r.y;
    }
    floatx4* o = (floatx4*)(enc_out + (size_t)i * (2 * NLEV));
    #pragma unroll
    for (int k = 0; k < (2 * NLEV) / 4; ++k) {
        floatx4 v = { enc[4 * k + 0], enc[4 * k + 1],
                      enc[4 * k + 2], enc[4 * k + 3] };
        __builtin_nontemporal_store(v, o + k);
    }
    __builtin_nontemporal_store(inb ? 1.0f : 0.0f, mask_out + i);
}

extern "C" void kernel_launch(void* const* d_in, const int* in_sizes, int n_in,
                              void* d_out, int out_size, void* d_ws, size_t ws_size,
                              hipStream_t stream) {
    const float* x     = (const float*)d_in[0];
    const float* bb    = (const float*)d_in[1];
    const float* table = (const float*)d_in[2];
    const int n = in_sizes[0] / 3;

    float* enc_out  = (float*)d_out;
    float* mask_out = enc_out + (size_t)n * (2 * NLEV);

    const size_t ws_need = (size_t)NLEV * (size_t)n * 2 * sizeof(float);
    if (ws_size >= ws_need) {
        float* ws = (float*)d_ws;
        const int chunks = (n + CHUNK1 - 1) / CHUNK1;
        const int grid1 = chunks * 8;
        level_kernel<<<grid1, BLOCK1, 0, stream>>>(x, bb, table, ws, n, 0);
        level_kernel<<<grid1, BLOCK1, 0, stream>>>(x, bb, table, ws, n, 8);
        const int grid2 = (n + 255) / 256;
        transpose_kernel<<<grid2, 256, 0, stream>>>(ws, x, bb, enc_out, mask_out, n);
    } else {
        const int grid = (n + 255) / 256;
        hashenc_direct<<<grid, 256, 0, stream>>>(x, bb, table, enc_out, mask_out, n);
    }
}